// Round 5
// baseline (12251.109 us; speedup 1.0000x reference)
//
#include <hip/hip_runtime.h>

typedef __attribute__((ext_vector_type(4))) float f32x4;
typedef __attribute__((ext_vector_type(8))) short s16x8;
typedef unsigned long long u64;
typedef unsigned short u16;

__device__ __forceinline__ u16 f2bf(float f) {
  union { float f; unsigned u; } v; v.f = f;
  unsigned r = v.u + 0x7fffu + ((v.u >> 16) & 1u);
  return (u16)(r >> 16);
}

// ---------------- prep kernels ----------------

// W1[c][256][512] bf16 = hcomb_W ; W2[c][768][256] bf16 = W_hh
__global__ void prep_w12(const float* __restrict__ hcomb_W, const float* __restrict__ W_hh,
                         u16* __restrict__ W1, u16* __restrict__ W2) {
  const int c = blockIdx.x, g = blockIdx.y, t = threadIdx.x; // grid (3,1024), block 256
  if (g < 256) {
    const float* src = hcomb_W + ((size_t)c * 256 + g) * 512;
    u16* dst = W1 + ((size_t)c * 256 + g) * 512;
    dst[t] = f2bf(src[t]); dst[t + 256] = f2bf(src[t + 256]);
  } else {
    const int gp = g - 256;
    W2[((size_t)c * 768 + gp) * 256 + t] = f2bf(W_hh[((size_t)c * 768 + gp) * 256 + t]);
  }
}

// U_{l,a}[c][v][f] = sum_e emb[c][v][e] * xcomb_W[c][f][side*256 + e]
__global__ void prep_u(const float* __restrict__ emb, const float* __restrict__ xcomb_W,
                       float* __restrict__ Ul, float* __restrict__ Ua) {
  __shared__ float er[256];
  const int c = blockIdx.x, v = blockIdx.y, side = blockIdx.z, f = threadIdx.x;
  er[f] = emb[((size_t)c * 257 + v) * 256 + f];
  __syncthreads();
  const float* wrow = xcomb_W + ((size_t)c * 256 + f) * 512 + side * 256;
  float a = 0.f;
  for (int e = 0; e < 256; e++) a += er[e] * wrow[e];
  (side ? Ua : Ul)[((size_t)c * 257 + v) * 256 + f] = a;
}

// T_{l,a}[c][v][g] (f32) = sum_f W_ih[c][g][f] * U[c][v][f]
__global__ void prep_t(const float* __restrict__ W_ih, const float* __restrict__ Ul,
                       const float* __restrict__ Ua, float* __restrict__ Tl, float* __restrict__ Ta) {
  __shared__ float ur[256];
  const int c = blockIdx.x, v = blockIdx.y, side = blockIdx.z, g = threadIdx.x; // block 768
  if (g < 256) ur[g] = (side ? Ua : Ul)[((size_t)c * 257 + v) * 256 + g];
  __syncthreads();
  const float* wrow = W_ih + ((size_t)c * 768 + g) * 258;
  float a = 0.f;
  for (int f = 0; f < 256; f++) a += ur[f] * wrow[f];
  (side ? Ta : Tl)[((size_t)c * 257 + v) * 768 + g] = a;
}

// bgx[c][g] = b_ih[c][g] + sum_f W_ih[c][g][f] * xcomb_b[c][f]
__global__ void prep_bgx(const float* __restrict__ W_ih, const float* __restrict__ xcomb_b,
                         const float* __restrict__ b_ih, float* __restrict__ bgx) {
  __shared__ float xb[256];
  const int c = blockIdx.x, g = threadIdx.x; // block 768
  if (g < 256) xb[g] = xcomb_b[c * 256 + g];
  __syncthreads();
  const float* wrow = W_ih + ((size_t)c * 768 + g) * 258;
  float a = b_ih[c * 768 + g];
  for (int f = 0; f < 256; f++) a += xb[f] * wrow[f];
  bgx[c * 768 + g] = a;
}

// TG[v][u] = emb[0][v].green_W[u][256:512]; TB0 = emb[0].blue[256:512]; TB1 = emb[1].blue[512:768]
__global__ void prep_tgb(const float* __restrict__ emb, const float* __restrict__ green_W,
                         const float* __restrict__ blue_W,
                         float* __restrict__ TG, float* __restrict__ TB0, float* __restrict__ TB1) {
  __shared__ float er[256];
  const int v = blockIdx.x, which = blockIdx.y, u = threadIdx.x; // block 320
  const int ch = (which == 2) ? 1 : 0;
  if (u < 256) er[u] = emb[((size_t)ch * 257 + v) * 256 + u];
  __syncthreads();
  if (u >= 257) return;
  const float* W; int pitch, off; float* T;
  if (which == 0)      { W = green_W; pitch = 512; off = 256; T = TG;  }
  else if (which == 1) { W = blue_W;  pitch = 768; off = 256; T = TB0; }
  else                 { W = blue_W;  pitch = 768; off = 512; T = TB1; }
  const float* wrow = W + (size_t)u * pitch + off;
  float a = 0.f;
  for (int e = 0; e < 256; e++) a += er[e] * wrow[e];
  T[(size_t)v * 257 + u] = a;
}

// W3[c] (272x256) bf16 = h-part of {red_W, green_W, blue_W}; rows >=257 zero
__global__ void prep_w3(const float* __restrict__ red_W, const float* __restrict__ green_W,
                        const float* __restrict__ blue_W, u16* __restrict__ W3) {
  const int c = blockIdx.x, v = blockIdx.y, t = threadIdx.x; // block 256
  float val = 0.f;
  if (v < 257) {
    if (c == 0)      val = red_W[(size_t)v * 256 + t];
    else if (c == 1) val = green_W[(size_t)v * 512 + t];
    else             val = blue_W[(size_t)v * 768 + t];
  }
  W3[((size_t)c * 272 + v) * 256 + t] = f2bf(val);
}

__global__ void zero_flags(int* __restrict__ f, int n) {
  int i = blockIdx.x * 256 + threadIdx.x;
  if (i < n) f[i] = 0;
}

// ---------------- persistent wavefront kernel ----------------
// One 1024-thread block per ROW (step, CUs 0..30) + one per row (epi, CUs 31..61).
// In-row recurrence is CU-internal: h ping-pongs between two 64KB LDS regions; only
// the cross-row "above" edge goes through L3 (bf16 WT stores + relaxed agent flags —
// the round-2/3 proven scheme; zero cache-maintenance ops in the loop).

__device__ __forceinline__ void spinwait(int* f, int target) {
  for (long i = 0; i < 200000000L; ++i) {   // bounded: a flag bug fails numerics, not the container
    if (__hip_atomic_load(f, __ATOMIC_RELAXED, __HIP_MEMORY_SCOPE_AGENT) >= target) return;
    __builtin_amdgcn_s_sleep(2);
  }
}
__device__ __forceinline__ u64 load_coh(const u16* p) {
  return __hip_atomic_load((const u64*)p, __ATOMIC_RELAXED, __HIP_MEMORY_SCOPE_SYSTEM);
}
__device__ __forceinline__ void store_coh(u16* p, u64 v) {
  __hip_atomic_store((u64*)p, v, __ATOMIC_RELAXED, __HIP_MEMORY_SCOPE_SYSTEM);
}
// XOR-swizzled offset inside a 128x256-bf16 (64KB) region
__device__ __forceinline__ int sw_off(int row, int el) {
  return row * 512 + ((el * 2) ^ ((row & 7) << 4));
}

__global__ __launch_bounds__(1024, 1)
void persist_kernel(const int* __restrict__ x, u16* __restrict__ hbuf,
                    const u16* __restrict__ W1, const u16* __restrict__ W2,
                    const float* __restrict__ Tl, const float* __restrict__ Ta,
                    const float* __restrict__ bgx, const float* __restrict__ W_ih,
                    const float* __restrict__ hcomb_b, const float* __restrict__ b_hh,
                    const u16* __restrict__ W3,
                    const float* __restrict__ TG, const float* __restrict__ TB0,
                    const float* __restrict__ TB1,
                    const float* __restrict__ red_b, const float* __restrict__ green_b,
                    const float* __restrict__ blue_b,
                    float* __restrict__ out, int* __restrict__ flags)
{
  __shared__ char smem[131072];     // two 64KB ping-pong regions (step) / h stage (epi)
  __shared__ int idx0[128];
  __shared__ int idx1[128];

  int* sflag = flags;              // [124][31]
  int* eflag = flags + 124 * 31;   // [124][31]

  const int id = blockIdx.x;
  const int tid = threadIdx.x;
  const int w = tid >> 6, lane = tid & 63, quad = lane >> 4, l16 = lane & 15;

  if (id < 31) {
    // ================= step row r: levels L = r .. r+92 =================
    const int r = id;
    const int wm = w >> 3, wj = w & 7;          // 2 (batch-half) x 8 (j-slice) waves
    const int arow = wm * 64 + l16;             // A-fragment row base (+mi*16)

    for (int L = r; L <= r + 92; ++L) {
      const int t = L - r;
      const int k = t / 3, c = t - 3 * k;
      char* Pr = smem + ((t & 1) ? 65536 : 0);  // pl / h-gate region
      char* Or = smem + ((t & 1) ? 0 : 65536);  // above region, then h' destination

      if (tid == 0) {
        if (r >= 1) spinwait(&sflag[(L - 1) * 31 + (r - 1)], 1);
        if (t >= 3) {
          if (r < 30) spinwait(&sflag[(L - 2) * 31 + (r + 1)], 1);
          spinwait(&eflag[(L - 2) * 31 + r], 1);
        }
      }
      __syncthreads();                                           // bar1
      __builtin_amdgcn_fence(__ATOMIC_ACQUIRE, "workgroup");

      const bool pl_zero = (t == 0);
      const bool a_zero  = (r == 0);

      // issue above-h loads (coherent bf16 from L3); overlap GEMM1 part1
      u64 sa0[4], sa1[4];
      if (!a_zero) {
        const u16* hgA = hbuf + (size_t)((r - 1) * 3 + c) * 32768;
        #pragma unroll
        for (int q = 0; q < 4; ++q) {
          const int ch = q * 1024 + tid, row = ch >> 5, cs = ch & 31;
          const u16* sp = hgA + row * 256 + cs * 8;
          sa0[q] = load_coh(sp); sa1[q] = load_coh(sp + 4);
        }
      }
      if (tid < 128) {
        idx0[tid] = x[((tid * 3 + c) * 32 + (r + 1)) * 32 + k];       // left
        idx1[tid] = x[((tid * 3 + c) * 32 + r) * 32 + (k + 1)];       // above
      }

      // ---- GEMM1: h = [pl | above] @ hcombW.T (+bias later); K=512, N=256 ----
      const u16* W1c = W1 + (size_t)c * 256 * 512;
      f32x4 acc1[4][2];
      #pragma unroll
      for (int mi = 0; mi < 4; ++mi)
        #pragma unroll
        for (int ji = 0; ji < 2; ++ji)
          #pragma unroll
          for (int e = 0; e < 4; ++e) acc1[mi][ji][e] = 0.f;

      if (!pl_zero) {     // part1: k 0..255 (pl in Pr)
        #pragma unroll
        for (int kc = 0; kc < 2; ++kc)
          #pragma unroll
          for (int ks = 0; ks < 4; ++ks) {
            const int kof = kc * 128 + ks * 32 + quad * 8;
            s16x8 bf[2];
            #pragma unroll
            for (int ji = 0; ji < 2; ++ji)
              bf[ji] = *(const s16x8*)(W1c + (size_t)(ji * 128 + wj * 16 + l16) * 512 + kof);
            #pragma unroll
            for (int mi = 0; mi < 4; ++mi) {
              const s16x8 af = *(const s16x8*)(Pr + sw_off(arow + mi * 16, kof));
              #pragma unroll
              for (int ji = 0; ji < 2; ++ji)
                acc1[mi][ji] = __builtin_amdgcn_mfma_f32_16x16x32_bf16(af, bf[ji], acc1[mi][ji], 0, 0, 0);
            }
          }
      }
      if (!a_zero) {      // write above into Or
        #pragma unroll
        for (int q = 0; q < 4; ++q) {
          const int ch = q * 1024 + tid, row = ch >> 5, cs = ch & 31;
          const int s = sw_off(row, cs * 8);
          *(u64*)(Or + s) = sa0[q]; *(u64*)(Or + s + 8) = sa1[q];
        }
      }
      __syncthreads();                                           // bar2

      if (!a_zero) {      // part2: k 256..511 (above in Or)
        #pragma unroll
        for (int kc = 0; kc < 2; ++kc)
          #pragma unroll
          for (int ks = 0; ks < 4; ++ks) {
            const int ke = kc * 128 + ks * 32 + quad * 8;
            s16x8 bf[2];
            #pragma unroll
            for (int ji = 0; ji < 2; ++ji)
              bf[ji] = *(const s16x8*)(W1c + (size_t)(ji * 128 + wj * 16 + l16) * 512 + 256 + ke);
            #pragma unroll
            for (int mi = 0; mi < 4; ++mi) {
              const s16x8 af = *(const s16x8*)(Or + sw_off(arow + mi * 16, ke));
              #pragma unroll
              for (int ji = 0; ji < 2; ++ji)
                acc1[mi][ji] = __builtin_amdgcn_mfma_f32_16x16x32_bf16(af, bf[ji], acc1[mi][ji], 0, 0, 0);
            }
          }
      }
      // write h-gate bf16 into Pr (GEMM2's A); f32 h stays in acc1 for the z*h term
      #pragma unroll
      for (int ji = 0; ji < 2; ++ji) {
        const int j = ji * 128 + wj * 16 + l16;
        const float bh = hcomb_b[c * 256 + j];
        #pragma unroll
        for (int mi = 0; mi < 4; ++mi)
          #pragma unroll
          for (int ii = 0; ii < 4; ++ii) {
            const int b = (wm * 4 + mi) * 16 + quad * 4 + ii;
            *(u16*)(Pr + sw_off(b, j)) = f2bf(acc1[mi][ji][ii] + bh);
          }
      }
      __syncthreads();                                           // bar3

      // ---- GEMM2: gh = h @ W_hh.T (K=256,N=768) + GRU combine; h' -> Or ----
      const u16* W2c = W2 + (size_t)c * 768 * 256;
      const float* Tlc = Tl + (size_t)c * 257 * 768;
      const float* Tac = Ta + (size_t)c * 257 * 768;
      const float fr = (float)r, fk = (float)k;

      #pragma unroll
      for (int jh = 0; jh < 2; ++jh) {
        const int j2 = jh * 128 + wj * 16 + l16;
        float gx0[3], bh3[3];
        #pragma unroll
        for (int q = 0; q < 3; ++q) {
          const int gi = c * 768 + q * 256 + j2;
          gx0[q] = bgx[gi] + fr * W_ih[(size_t)gi * 258 + 256] + fk * W_ih[(size_t)gi * 258 + 257];
          bh3[q] = b_hh[gi];
        }
        const float bh2 = hcomb_b[c * 256 + j2];

        // gathers folded into MFMA C-init (r,z fully; n keeps gxn separate)
        f32x4 acc2[4][3];
        float gxn[4][4];
        #pragma unroll
        for (int mi = 0; mi < 4; ++mi)
          #pragma unroll
          for (int ii = 0; ii < 4; ++ii) {
            const int b = (wm * 4 + mi) * 16 + quad * 4 + ii;
            const float* tl = Tlc + (size_t)idx0[b] * 768 + j2;
            const float* ta = Tac + (size_t)idx1[b] * 768 + j2;
            acc2[mi][0][ii] = gx0[0] + tl[0]   + ta[0]   + bh3[0];
            acc2[mi][1][ii] = gx0[1] + tl[256] + ta[256] + bh3[1];
            acc2[mi][2][ii] = bh3[2];
            gxn[mi][ii]     = gx0[2] + tl[512] + ta[512];
          }

        #pragma unroll
        for (int ks = 0; ks < 8; ++ks) {
          const int kof = ks * 32 + quad * 8;
          s16x8 bf[3];
          #pragma unroll
          for (int q = 0; q < 3; ++q)
            bf[q] = *(const s16x8*)(W2c + (size_t)(q * 256 + j2) * 256 + kof);
          #pragma unroll
          for (int mi = 0; mi < 4; ++mi) {
            const s16x8 af = *(const s16x8*)(Pr + sw_off(arow + mi * 16, kof));
            #pragma unroll
            for (int q = 0; q < 3; ++q)
              acc2[mi][q] = __builtin_amdgcn_mfma_f32_16x16x32_bf16(af, bf[q], acc2[mi][q], 0, 0, 0);
          }
        }

        #pragma unroll
        for (int mi = 0; mi < 4; ++mi)
          #pragma unroll
          for (int ii = 0; ii < 4; ++ii) {
            const int b = (wm * 4 + mi) * 16 + quad * 4 + ii;
            const float h  = acc1[mi][jh][ii] + bh2;                     // f32 h
            const float rg = __fdividef(1.f, 1.f + __expf(-acc2[mi][0][ii]));
            const float zg = __fdividef(1.f, 1.f + __expf(-acc2[mi][1][ii]));
            const float ng = 1.f - __fdividef(2.f,
                __expf(2.f * (gxn[mi][ii] + rg * acc2[mi][2][ii])) + 1.f);
            *(u16*)(Or + sw_off(b, j2)) = f2bf((1.f - zg) * ng + zg * h); // h' -> Or
          }
      }
      __syncthreads();                                           // bar4

      // bulk copy h' -> global (coherent bf16 WT, linear layout)
      u16* hgW = hbuf + (size_t)(r * 3 + c) * 32768;
      #pragma unroll
      for (int q = 0; q < 4; ++q) {
        const int ch = q * 1024 + tid, row = ch >> 5, cs = ch & 31;
        const int s = sw_off(row, cs * 8);
        store_coh(hgW + row * 256 + cs * 8,     *(const u64*)(Or + s));
        store_coh(hgW + row * 256 + cs * 8 + 4, *(const u64*)(Or + s + 8));
      }
      __syncthreads();                                           // bar5 (drains vmcnt)
      if (tid == 0)
        __hip_atomic_fetch_add(&sflag[L * 31 + r], 1, __ATOMIC_RELAXED, __HIP_MEMORY_SCOPE_AGENT);
    }
  } else {
    // ================= epi row r: iters Le = r+1 .. r+93 (cell level Le-1) =================
    const int r = id - 31;
    const int wmE = w & 3, wnE = w >> 2;          // 4 (batch) x 4 (vocab) wave grid
    const int NT = wnE ? 4 : 5;
    const int nbase = wnE ? (1 + wnE * 4) : 0;

    for (int Le = r + 1; Le <= r + 93; ++Le) {
      const int t = Le - 1 - r;
      const int k = t / 3, c = t - 3 * k;

      if (tid == 0) spinwait(&sflag[(Le - 1) * 31 + r], 1);
      __syncthreads();
      __builtin_amdgcn_fence(__ATOMIC_ACQUIRE, "workgroup");

      // stage h (bf16, from L3) -> LDS + idx
      const u16* hgS = hbuf + (size_t)(r * 3 + c) * 32768;
      #pragma unroll
      for (int q = 0; q < 4; ++q) {
        const int ch = q * 1024 + tid, row = ch >> 5, cs = ch & 31;
        const u16* sp = hgS + row * 256 + cs * 8;
        const u64 a0 = load_coh(sp), a1 = load_coh(sp + 4);
        const int s = sw_off(row, cs * 8);
        *(u64*)(smem + s) = a0; *(u64*)(smem + s + 8) = a1;
      }
      if (tid < 128) {
        idx0[tid] = x[((tid * 3 + 0) * 32 + (r + 1)) * 32 + (k + 1)];  // target ch0
        idx1[tid] = x[((tid * 3 + 1) * 32 + (r + 1)) * 32 + (k + 1)];  // target ch1
      }
      __syncthreads();
      if (tid == 0)   // all hbuf reads for this cell complete -> unblock writer
        __hip_atomic_fetch_add(&eflag[Le * 31 + r], 1, __ATOMIC_RELAXED, __HIP_MEMORY_SCOPE_AGENT);

      const u16* W3c = W3 + (size_t)c * 272 * 256;
      f32x4 acc[2][5];
      #pragma unroll
      for (int mi = 0; mi < 2; ++mi)
        #pragma unroll
        for (int ni = 0; ni < 5; ++ni)
          #pragma unroll
          for (int e = 0; e < 4; ++e) acc[mi][ni][e] = 0.f;

      #pragma unroll
      for (int ks = 0; ks < 8; ++ks) {
        const int kof = ks * 32 + quad * 8;
        s16x8 af[2];
        #pragma unroll
        for (int mi = 0; mi < 2; ++mi)
          af[mi] = *(const s16x8*)(smem + sw_off((wmE * 2 + mi) * 16 + l16, kof));
        #pragma unroll
        for (int ni = 0; ni < 5; ++ni) {
          if (ni < NT) {
            const s16x8 bf = *(const s16x8*)(W3c + (size_t)((nbase + ni) * 16 + l16) * 256 + kof);
            #pragma unroll
            for (int mi = 0; mi < 2; ++mi)
              acc[mi][ni] = __builtin_amdgcn_mfma_f32_16x16x32_bf16(af[mi], bf, acc[mi][ni], 0, 0, 0);
          }
        }
      }

      const float* bias = (c == 0) ? red_b : (c == 1) ? green_b : blue_b;
      #pragma unroll
      for (int mi = 0; mi < 2; ++mi)
        #pragma unroll
        for (int ii = 0; ii < 4; ++ii) {
          const int b = (wmE * 2 + mi) * 16 + quad * 4 + ii;
          const int t0 = idx0[b], t1 = idx1[b];
          float* orow = out + ((size_t)((b * 3 + c) * 31 + r) * 31 + k) * 257;
          #pragma unroll
          for (int ni = 0; ni < 5; ++ni) {
            if (ni < NT) {
              const int v = (nbase + ni) * 16 + l16;
              if (v < 257) {
                float val = acc[mi][ni][ii] + bias[v];
                if (c == 1)      val += TG[(size_t)t0 * 257 + v];
                else if (c == 2) val += TB0[(size_t)t0 * 257 + v] + TB1[(size_t)t1 * 257 + v];
                orow[v] = val;
              }
            }
          }
        }
    }
  }
}

// ---------------- host launch ----------------

extern "C" void kernel_launch(void* const* d_in, const int* in_sizes, int n_in,
                              void* d_out, int out_size, void* d_ws, size_t ws_size,
                              hipStream_t stream) {
  const int*   x       = (const int*)  d_in[0];
  const float* emb     = (const float*)d_in[1];
  const float* xcomb_W = (const float*)d_in[2];
  const float* xcomb_b = (const float*)d_in[3];
  const float* hcomb_W = (const float*)d_in[4];
  const float* hcomb_b = (const float*)d_in[5];
  const float* W_ih    = (const float*)d_in[6];
  const float* W_hh    = (const float*)d_in[7];
  const float* b_ih    = (const float*)d_in[8];
  const float* b_hh    = (const float*)d_in[9];
  const float* red_W   = (const float*)d_in[10];
  const float* red_b   = (const float*)d_in[11];
  const float* green_W = (const float*)d_in[12];
  const float* green_b = (const float*)d_in[13];
  const float* blue_W  = (const float*)d_in[14];
  const float* blue_b  = (const float*)d_in[15];
  float* out = (float*)d_out;

  char* p = (char*)d_ws;
  auto alloc = [&](size_t bytes) -> char* {
    char* r = p; p += (bytes + 255) & ~(size_t)255; return r;
  };
  u16*   hbuf  = (u16*)  alloc((size_t)93 * 128 * 256 * 2);     // bf16 h hand-off
  u16*   W1    = (u16*)  alloc((size_t)3 * 256 * 512 * 2);
  u16*   W2    = (u16*)  alloc((size_t)3 * 768 * 256 * 2);
  float* Tl    = (float*)alloc((size_t)3 * 257 * 768 * 4);
  float* Ta    = (float*)alloc((size_t)3 * 257 * 768 * 4);
  float* Ul    = (float*)alloc((size_t)3 * 257 * 256 * 4);
  float* Ua    = (float*)alloc((size_t)3 * 257 * 256 * 4);
  float* bgx   = (float*)alloc((size_t)3 * 768 * 4);
  u16*   W3    = (u16*)  alloc((size_t)3 * 272 * 256 * 2);
  float* TG    = (float*)alloc((size_t)257 * 257 * 4);
  float* TB0   = (float*)alloc((size_t)257 * 257 * 4);
  float* TB1   = (float*)alloc((size_t)257 * 257 * 4);
  int*   flags = (int*)  alloc((size_t)2 * 124 * 31 * 4);

  prep_w12<<<dim3(3, 1024), dim3(256), 0, stream>>>(hcomb_W, W_hh, W1, W2);
  prep_u<<<dim3(3, 257, 2), dim3(256), 0, stream>>>(emb, xcomb_W, Ul, Ua);
  prep_t<<<dim3(3, 257, 2), dim3(768), 0, stream>>>(W_ih, Ul, Ua, Tl, Ta);
  prep_bgx<<<dim3(3), dim3(768), 0, stream>>>(W_ih, xcomb_b, b_ih, bgx);
  prep_tgb<<<dim3(257, 3), dim3(320), 0, stream>>>(emb, green_W, blue_W, TG, TB0, TB1);
  prep_w3<<<dim3(3, 272), dim3(256), 0, stream>>>(red_W, green_W, blue_W, W3);
  zero_flags<<<dim3(31), dim3(256), 0, stream>>>(flags, 2 * 124 * 31);

  // 62 blocks: 31 step rows + 31 epi rows, 1 block/CU (static 129KB LDS), all co-resident
  persist_kernel<<<dim3(62), dim3(1024), 0, stream>>>(
      x, hbuf, W1, W2, Tl, Ta, bgx, W_ih, hcomb_b, b_hh, W3, TG, TB0, TB1,
      red_b, green_b, blue_b, out, flags);
}